// Round 12
// baseline (49.485 us; speedup 1.0000x reference)
//
#include <hip/hip_runtime.h>

// FourierFilter2D: out[b,h,w,f] = Re( sum_c x[b,h,w,c] * W[c,h,w,f] ) + b_re[f]
// B=8, H=64, W=64, C=64, F=64. Output: [B][H][W][F] float32, REAL part only.
//
// r6-r11: 36.6 / 87 / 42 / 43.6 / 35.2 / 32.1 us. Lessons:
//  - steady-state (graph replay) is L3-resident (W+x = 151MB < 256MB L3);
//    the wall is outstanding-request concurrency, not HBM.
//  - r10: occupancy (74%) with 4B loads -> 35us. r11: 1KB loads with 35% occ
//    -> 32us. Need BOTH fat loads and full occupancy.
// This version: block = 512 threads = 8 waves = 4 hw x 8 b (one b per wave).
//  - W: dwordx4 streams, 1KB/instr (lane l covers bytes 16l of c-row's
//    4hw x 64f span). Each wave streams all 64 c; the block's 8 waves read
//    the SAME stream in lockstep -> L1/MSHR dedup.
//  - no cross-wave reduction (each wave owns complete c-sum for its b).
//  - LDS: only x stage, f32x2 xs[4][8][65] = 16.6KB -> occupancy capped by
//    waves (32/CU, 100%), not LDS. Pad 65: write banks 2c (2-way, free),
//    read banks +16 per hw_l (2-way, free).
//  - store: one f32x4 per wave (64 lanes x 16B = 4hw x 64f for its b).

typedef float f32x2v __attribute__((ext_vector_type(2)));
typedef float f32x4v __attribute__((ext_vector_type(4)));

constexpr int Bb = 8;
constexpr int C  = 64;
constexpr int F  = 64;
constexpr int HW  = 4096;
constexpr int HWC = HW * C;         // 262144
constexpr int HWF = HW * F;         // 262144

__global__ __launch_bounds__(512, 8) void fourier_filter2d_kernel(
    const float* __restrict__ x_re, const float* __restrict__ x_im,
    const float* __restrict__ w_re, const float* __restrict__ w_im,
    const float* __restrict__ b_re,
    float* __restrict__ out)
{
    __shared__ f32x2v xs[4][Bb][65];   // [hw_l][b][c], pad 65 -> 16640 B

    const int t   = threadIdx.x;       // 0..511
    const int hw0 = blockIdx.x * 4;

    // ---- Stage x for 4 hw (2048 float2). Lanes walk c -> 256B coalesced.
    #pragma unroll
    for (int i = 0; i < 4; ++i) {
        const int e  = t + i * 512;    // 0..2047
        const int c  = e & 63;
        const int hl = (e >> 6) & 3;
        const int b  = e >> 8;
        const size_t g = (size_t)b * HWC + (size_t)(hw0 + hl) * C + c;
        xs[hl][b][c] = (f32x2v){x_re[g], x_im[g]};
    }
    __syncthreads();

    const int wid  = t >> 6;        // wave id = b (0..7)
    const int lane = t & 63;
    const int hl   = lane >> 4;     // this lane's hw within the block
    const int f4   = lane & 15;     // f quad: f = f4*4 .. +3

    f32x4v acc = (f32x4v){0.f, 0.f, 0.f, 0.f};

    // W stream: per c one 1KB wave-load (lane l -> byte 16l of the
    // contiguous 4hw x 64f row block starting at (c*HW + hw0)*F).
    const float* __restrict__ wrb = w_re + (size_t)hw0 * F + lane * 4;
    const float* __restrict__ wib = w_im + (size_t)hw0 * F + lane * 4;

    #pragma unroll 8
    for (int c = 0; c < C; ++c) {
        const size_t o = (size_t)c * HWF;
        const f32x4v wr4 = *(const f32x4v*)(wrb + o);
        const f32x4v wi4 = *(const f32x4v*)(wib + o);
        const f32x2v xv  = xs[hl][wid][c];    // 4 addrs, 16-lane broadcast
        // Re((xr + i*xi)*(wr + i*wi)) = xr*wr - xi*wi
        acc = acc + wr4 * xv.x;
        acc = acc - wi4 * xv.y;
    }

    const f32x4v bias = *(const f32x4v*)(b_re + f4 * 4);
    *(f32x4v*)(out + (size_t)wid * HWF + (size_t)(hw0 + hl) * F + f4 * 4)
        = acc + bias;
}

extern "C" void kernel_launch(void* const* d_in, const int* in_sizes, int n_in,
                              void* d_out, int out_size, void* d_ws, size_t ws_size,
                              hipStream_t stream) {
    const float* x_re = (const float*)d_in[0];
    const float* x_im = (const float*)d_in[1];
    const float* w_re = (const float*)d_in[2];
    const float* w_im = (const float*)d_in[3];
    const float* b_re = (const float*)d_in[4];
    float* out = (float*)d_out;

    const int blocks = HW / 4; // 1024 blocks x 8 waves = 8192 waves = 32/CU
    fourier_filter2d_kernel<<<blocks, 512, 0, stream>>>(
        x_re, x_im, w_re, w_im, b_re, out);
}

// Round 13
// 30.449 us; speedup vs baseline: 1.6252x; 1.6252x over previous
//
#include <hip/hip_runtime.h>

// FourierFilter2D: out[b,h,w,f] = Re( sum_c x[b,h,w,c] * W[c,h,w,f] ) + b_re[f]
// B=8, H=64, W=64, C=64, F=64. Output: [B][H][W][F] float32, REAL part only.
//
// r6-r12: 36.6 / 87 / 42 / 43.6 / 35.2 / 32.1 / 49.5 us. Established rules:
//  - W must be fetched EXACTLY once per block (r12: 8x dup -> 49.5us).
//  - fat loads (dwordx4) beat thin (r11 vs r10).
//  - LDS broadcast instrs are ~8cyc each -> minimize count (r6 disease).
// r13 = r11 skeleton, refined:
//  - W loads NON-TEMPORAL: W is single-use per dispatch; keep it out of
//    L2/L3 so x stays resident and W streams at pure-HBM rate (~6.3TB/s).
//  - x reads as b128 (c-pair per instr): 64 LDS reads/wave, conflict-free
//    via xs[b][hl][66] (hl groups hit disjoint bank quads: 132%32=4).
//  - partials as part[j=b*4+jj][t]: writes coalesced conflict-free,
//    reads 4-way max (was 655K conflict cycles in r11).
// Block = 4 waves x 4 hw; wave wid owns c-quarter [16*wid,16*wid+16).
// Grid 1024 = 4 blocks/CU, whole grid co-resident. LDS 32KB.

typedef float f32x2v __attribute__((ext_vector_type(2)));
typedef float f32x4v __attribute__((ext_vector_type(4)));

constexpr int Bb = 8;
constexpr int C  = 64;
constexpr int F  = 64;
constexpr int HW  = 4096;
constexpr int HWC = HW * C;         // 262144
constexpr int HWF = HW * F;         // 262144

__global__ __launch_bounds__(256, 4) void fourier_filter2d_kernel(
    const float* __restrict__ x_re, const float* __restrict__ x_im,
    const float* __restrict__ w_re, const float* __restrict__ w_im,
    const float* __restrict__ b_re,
    float* __restrict__ out)
{
    // 32KB, time-multiplexed:
    //  phase A: f32x2 xs[b][hl][66]  (idx (b*4+hl)*66 + c)      16896 B
    //  phase B: float part[32][256]  (idx (b*4+jj)*256 + t)     32768 B
    __shared__ __align__(16) float smem[8192];
    f32x2v* xs = (f32x2v*)smem;

    const int t    = threadIdx.x;
    const int wid  = t >> 6;
    const int lane = t & 63;
    const int hw0  = blockIdx.x * 4;

    // ---- Stage x for 4 hw (2048 f32x2). 2 chunks/thread, dwordx4 loads.
    #pragma unroll
    for (int k = 0; k < 2; ++k) {
        const int chunk = t + k * 256;        // b(8) x hl(4) x c4(16)
        const int b  = chunk >> 6;
        const int r  = chunk & 63;
        const int hl = r >> 4;
        const int c4 = (r & 15) * 4;
        const size_t g = (size_t)b * HWC + (size_t)(hw0 + hl) * C + c4;
        const f32x4v vr = *(const f32x4v*)(x_re + g);
        const f32x4v vi = *(const f32x4v*)(x_im + g);
        const int base = (b * 4 + hl) * 66 + c4;   // f32x2 units, even -> 16B ok
        *(f32x4v*)&xs[base]     = (f32x4v){vr.x, vi.x, vr.y, vi.y};
        *(f32x4v*)&xs[base + 2] = (f32x4v){vr.z, vi.z, vr.w, vi.w};
    }
    __syncthreads();

    // ---- Compute: wave wid covers c in [wid*16, wid*16+16), as 8 c-pairs.
    const int hl = lane >> 4;            // lane's hw within block
    const int xbase0 = hl * 66;          // + b*264 + c

    f32x4v acc[Bb];
    #pragma unroll
    for (int b = 0; b < Bb; ++b) acc[b] = (f32x4v){0.f, 0.f, 0.f, 0.f};

    const float* __restrict__ wrb = w_re + (size_t)hw0 * F + lane * 4;
    const float* __restrict__ wib = w_im + (size_t)hw0 * F + lane * 4;

    #pragma unroll 4
    for (int cp = 0; cp < 8; ++cp) {
        const int c = wid * 16 + cp * 2;
        const size_t o0 = (size_t)c * HWF;
        const size_t o1 = o0 + HWF;
        // Non-temporal 1KB W loads (single-use data: bypass cache retention).
        const f32x4v wr0 = __builtin_nontemporal_load((const f32x4v*)(wrb + o0));
        const f32x4v wi0 = __builtin_nontemporal_load((const f32x4v*)(wib + o0));
        const f32x4v wr1 = __builtin_nontemporal_load((const f32x4v*)(wrb + o1));
        const f32x4v wi1 = __builtin_nontemporal_load((const f32x4v*)(wib + o1));
        #pragma unroll
        for (int b = 0; b < Bb; ++b) {
            // {xr(c), xi(c), xr(c+1), xi(c+1)} in one b128 (broadcast/16 lanes)
            const f32x4v xp = *(const f32x4v*)&xs[xbase0 + b * 264 + c];
            acc[b] = acc[b] + wr0 * xp.x;
            acc[b] = acc[b] - wi0 * xp.y;
            acc[b] = acc[b] + wr1 * xp.z;
            acc[b] = acc[b] - wi1 * xp.w;
        }
    }

    // ---- Cross-wave c-reduction via LDS partials (alias xs; fenced).
    __syncthreads();
    #pragma unroll
    for (int b = 0; b < Bb; ++b) {
        #pragma unroll
        for (int j = 0; j < 4; ++j)
            smem[(b * 4 + j) * 256 + t] = acc[b][j];   // coalesced, no conflict
    }
    __syncthreads();

    // ---- Phase 2: wave wid -> hw = hw0+wid; lane -> f.
    const int f    = lane;
    const int lsrc = wid * 16 + (f >> 2);
    const int jo   = f & 3;
    const float bias = b_re[f];

    #pragma unroll
    for (int b = 0; b < Bb; ++b) {
        const int row = (b * 4 + jo) * 256;
        float s = (smem[row + lsrc] + smem[row + 64 + lsrc])
                + (smem[row + 128 + lsrc] + smem[row + 192 + lsrc]);
        __builtin_nontemporal_store(s + bias,
            out + (size_t)b * HWF + (size_t)(hw0 + wid) * F + f);
    }
}

extern "C" void kernel_launch(void* const* d_in, const int* in_sizes, int n_in,
                              void* d_out, int out_size, void* d_ws, size_t ws_size,
                              hipStream_t stream) {
    const float* x_re = (const float*)d_in[0];
    const float* x_im = (const float*)d_in[1];
    const float* w_re = (const float*)d_in[2];
    const float* w_im = (const float*)d_in[3];
    const float* b_re = (const float*)d_in[4];
    float* out = (float*)d_out;

    const int blocks = HW / 4; // 1024 blocks x 4 waves = whole grid co-resident
    fourier_filter2d_kernel<<<blocks, 256, 0, stream>>>(
        x_re, x_im, w_re, w_im, b_re, out);
}

// Round 14
// 28.979 us; speedup vs baseline: 1.7076x; 1.0507x over previous
//
#include <hip/hip_runtime.h>

// FourierFilter2D: out[b,h,w,f] = Re( sum_c x[b,h,w,c] * W[c,h,w,f] ) + b_re[f]
// B=8, H=64, W=64, C=64, F=64. Output: [B][H][W][F] float32, REAL part only.
//
// r6-r13: 36.6 / 87 / 42 / 43.6 / 35.2 / 32.1 / 49.5 / 30.4 us. Rules learned:
//  - W fetched EXACTLY once per block (r12: dup -> 49.5).
//  - dwordx4 (1KB/wave) W streams; nt-loads for single-use W (r13: -1.7us).
//  - minimize LDS broadcast instr count; keep partial layouts conflict-free.
// r14 = r13 + (a) W-prefetch pipeline: cp0's loads issue BEFORE x-stage +
// barrier (W stream starts at cycle 0; 16.8MB x-burst hides under W latency;
// all 1024 blocks are co-resident = one generation, so prologue was serial),
// (b) fully conflict-free partials: addr ((b*4+wv)*4+hl)*65 + q*4+j ->
// writes (hl+4q)%32 = 2 lanes/bank, reads f%32 = 2 lanes/bank (both free).
//
// Block = 4 waves x 4 hw; wave wid owns c-quarter [16wid,16wid+16) as 8 c-pairs.
// Grid 1024 blocks (4/CU, LDS 33.3KB). launch_bounds(256,4) -> VGPR<=128.

typedef float f32x2v __attribute__((ext_vector_type(2)));
typedef float f32x4v __attribute__((ext_vector_type(4)));

constexpr int Bb = 8;
constexpr int C  = 64;
constexpr int F  = 64;
constexpr int HW  = 4096;
constexpr int HWC = HW * C;         // 262144
constexpr int HWF = HW * F;         // 262144

__global__ __launch_bounds__(256, 4) void fourier_filter2d_kernel(
    const float* __restrict__ x_re, const float* __restrict__ x_im,
    const float* __restrict__ w_re, const float* __restrict__ w_im,
    const float* __restrict__ b_re,
    float* __restrict__ out)
{
    // Time-multiplexed LDS:
    //  phase A: f32x2 xs[(b*4+hl)*66 + c]            -> 2112 f32x2 = 16896 B
    //  phase B: float part[((b*4+wv)*4+hl)*65 + f]   -> 8319 floats = 33276 B
    __shared__ __align__(16) float smem[8320];
    f32x2v* xs = (f32x2v*)smem;

    const int t    = threadIdx.x;
    const int wid  = t >> 6;
    const int lane = t & 63;
    const int hw0  = blockIdx.x * 4;

    const float* __restrict__ wrb = w_re + (size_t)hw0 * F + lane * 4;
    const float* __restrict__ wib = w_im + (size_t)hw0 * F + lane * 4;
    const float bias = b_re[lane];

    // ---- W prefetch for cp=0 (before x-stage: stream starts immediately).
    const int c_base = wid * 16;
    size_t o0 = (size_t)c_base * HWF;
    f32x4v nWr0 = __builtin_nontemporal_load((const f32x4v*)(wrb + o0));
    f32x4v nWi0 = __builtin_nontemporal_load((const f32x4v*)(wib + o0));
    f32x4v nWr1 = __builtin_nontemporal_load((const f32x4v*)(wrb + o0 + HWF));
    f32x4v nWi1 = __builtin_nontemporal_load((const f32x4v*)(wib + o0 + HWF));

    // ---- Stage x for 4 hw (2048 f32x2). 2 chunks/thread, dwordx4 loads.
    #pragma unroll
    for (int k = 0; k < 2; ++k) {
        const int chunk = t + k * 256;        // b(8) x hl(4) x c4(16)
        const int b  = chunk >> 6;
        const int r  = chunk & 63;
        const int hl = r >> 4;
        const int c4 = (r & 15) * 4;
        const size_t g = (size_t)b * HWC + (size_t)(hw0 + hl) * C + c4;
        const f32x4v vr = *(const f32x4v*)(x_re + g);
        const f32x4v vi = *(const f32x4v*)(x_im + g);
        const int base = (b * 4 + hl) * 66 + c4;   // f32x2 units (even -> 16B ok)
        *(f32x4v*)&xs[base]     = (f32x4v){vr.x, vi.x, vr.y, vi.y};
        *(f32x4v*)&xs[base + 2] = (f32x4v){vr.z, vi.z, vr.w, vi.w};
    }
    __syncthreads();

    // ---- Compute: 8 c-pairs, 1-deep W prefetch pipeline.
    const int hl = lane >> 4;            // lane's hw within block
    const int xbase0 = hl * 66;          // + b*264 + c (f32x2 units)

    f32x4v acc[Bb];
    #pragma unroll
    for (int b = 0; b < Bb; ++b) acc[b] = (f32x4v){0.f, 0.f, 0.f, 0.f};

    #pragma unroll
    for (int cp = 0; cp < 8; ++cp) {
        const f32x4v Wr0 = nWr0, Wi0 = nWi0, Wr1 = nWr1, Wi1 = nWi1;
        if (cp < 7) {
            const size_t o = (size_t)(c_base + (cp + 1) * 2) * HWF;
            nWr0 = __builtin_nontemporal_load((const f32x4v*)(wrb + o));
            nWi0 = __builtin_nontemporal_load((const f32x4v*)(wib + o));
            nWr1 = __builtin_nontemporal_load((const f32x4v*)(wrb + o + HWF));
            nWi1 = __builtin_nontemporal_load((const f32x4v*)(wib + o + HWF));
        }
        const int c = c_base + cp * 2;
        #pragma unroll
        for (int b = 0; b < Bb; ++b) {
            // {xr(c), xi(c), xr(c+1), xi(c+1)} in one b128 (broadcast /16 lanes)
            const f32x4v xp = *(const f32x4v*)&xs[xbase0 + b * 264 + c];
            acc[b] = acc[b] + Wr0 * xp.x;
            acc[b] = acc[b] - Wi0 * xp.y;
            acc[b] = acc[b] + Wr1 * xp.z;
            acc[b] = acc[b] - Wi1 * xp.w;
        }
    }

    // ---- Cross-wave c-reduction, conflict-free partials (alias xs; fenced).
    __syncthreads();
    {
        const int q = lane & 15;
        #pragma unroll
        for (int b = 0; b < Bb; ++b) {
            const int rowbase = ((b * 4 + wid) * 4 + hl) * 65 + q * 4;
            #pragma unroll
            for (int j = 0; j < 4; ++j)
                smem[rowbase + j] = acc[b][j];   // banks (hl+4q)%32: 2/bank, free
        }
    }
    __syncthreads();

    // ---- Phase 2: wave wid -> hw = hw0+wid; lane -> f. Reads conflict-free.
    const int f = lane;
    #pragma unroll
    for (int b = 0; b < Bb; ++b) {
        const int rb = (b * 4) * 4 + wid;
        float s = (smem[(rb + 0) * 65 + f] + smem[(rb + 4) * 65 + f])
                + (smem[(rb + 8) * 65 + f] + smem[(rb + 12) * 65 + f]);
        __builtin_nontemporal_store(s + bias,
            out + (size_t)b * HWF + (size_t)(hw0 + wid) * F + f);
    }
}

extern "C" void kernel_launch(void* const* d_in, const int* in_sizes, int n_in,
                              void* d_out, int out_size, void* d_ws, size_t ws_size,
                              hipStream_t stream) {
    const float* x_re = (const float*)d_in[0];
    const float* x_im = (const float*)d_in[1];
    const float* w_re = (const float*)d_in[2];
    const float* w_im = (const float*)d_in[3];
    const float* b_re = (const float*)d_in[4];
    float* out = (float*)d_out;

    const int blocks = HW / 4; // 1024 blocks x 4 waves, all co-resident
    fourier_filter2d_kernel<<<blocks, 256, 0, stream>>>(
        x_re, x_im, w_re, w_im, b_re, out);
}